// Round 4
// baseline (724.334 us; speedup 1.0000x reference)
//
#include <hip/hip_runtime.h>
#include <cstddef>

#define NPTS 500000
#define DF 64
#define NC 10000
#define BN_EPS 1e-5f

#define TPB 256
#define PTILE 128
#define NTILES ((NPTS + PTILE - 1) / PTILE)  // 3907
#define NBLK 768
#define LSTR 68  // xs row stride: 68 -> 8 rows/wave hit all 32 banks once

// ---- order-preserving float<->uint encoding (for atomic max on floats) ----
__device__ __forceinline__ unsigned f2o(float f) {
  unsigned u = __float_as_uint(f);
  return (u & 0x80000000u) ? ~u : (u | 0x80000000u);
}
__device__ __forceinline__ float o2f(unsigned u) {
  return __uint_as_float((u & 0x80000000u) ? (u ^ 0x80000000u) : ~u);
}

// ws layout (float/uint units):
// 0        : q_u     [NC*DF]   sortable-uint segment max of Q projections
// 640000   : mmax_u  [NC]      sortable-uint segment max of M
// 650000   : denom   [NC]      segment sum of exp
// 660000   : sums    [2*DF]    [sum h | sum h^2]
// 660128   : scale   [DF]
// 660192   : shift   [DF]
// 660256   : Mv      [NPTS]

// MODE 0: Q proj -> segment max into q_u (read-filtered atomics)
// MODE 1: K proj -> M = dot(q[c],k), store Mv, filtered atomicMax mmax_u
// MODE 2: V proj -> h = attn*v, accumulate BN stats (no h store)
// MODE 3: V proj -> h, normalize + relu, write out
//
// Thread tile: 4 points x 8 features (fg = tid&7 -> features fg*8..+7,
// pg = tid>>3 -> points pg*4..+3). 12 ds_read_b128 per 128 FMAs.
// Next x-tile prefetched into registers during compute (latency overlap).
#define FMA_K(PP, XC, E)                                    \
  acca[PP].x = fmaf(XC, wv[E][0].x, acca[PP].x);            \
  acca[PP].y = fmaf(XC, wv[E][0].y, acca[PP].y);            \
  acca[PP].z = fmaf(XC, wv[E][0].z, acca[PP].z);            \
  acca[PP].w = fmaf(XC, wv[E][0].w, acca[PP].w);            \
  accb[PP].x = fmaf(XC, wv[E][1].x, accb[PP].x);            \
  accb[PP].y = fmaf(XC, wv[E][1].y, accb[PP].y);            \
  accb[PP].z = fmaf(XC, wv[E][1].z, accb[PP].z);            \
  accb[PP].w = fmaf(XC, wv[E][1].w, accb[PP].w);

template <int MODE>
__launch_bounds__(TPB, 3)
__global__ void proj_kernel(
    const float* __restrict__ x, const int* __restrict__ cluster,
    const float* __restrict__ W, const float* __restrict__ bias,
    unsigned* __restrict__ q_u, unsigned* __restrict__ mmax_u,
    const float* __restrict__ denom, float* __restrict__ Mv,
    float* __restrict__ sums, const float* __restrict__ scale,
    const float* __restrict__ shift, float* __restrict__ out) {
  __shared__ float Wt[DF * DF];       // Wt[j][f] = W[f][j]; unpadded: reads
                                      // are 2-way/broadcast only (free)
  __shared__ float xs[PTILE * LSTR];  // xs[p][j]
  __shared__ int cs[PTILE];

  const int tid = threadIdx.x;
  const int fg = tid & 7;  // feature group -> features f0..f0+7
  const int pg = tid >> 3; // point group  -> points pg*4..+3
  const int f0 = fg * 8;

  // ---- stage W transposed (once per block) ----
  {
    const int f = tid & 63;
    const int jb = (tid >> 6) * 16;
#pragma unroll
    for (int i = 0; i < 4; ++i) {
      float4 wr = *(const float4*)(W + f * DF + jb + i * 4);
      Wt[(jb + i * 4 + 0) * DF + f] = wr.x;
      Wt[(jb + i * 4 + 1) * DF + f] = wr.y;
      Wt[(jb + i * 4 + 2) * DF + f] = wr.z;
      Wt[(jb + i * 4 + 3) * DF + f] = wr.w;
    }
  }
  const float4 bva = *(const float4*)(bias + f0);
  const float4 bvb = *(const float4*)(bias + f0 + 4);
  float4 sca = make_float4(0.f, 0.f, 0.f, 0.f), scb = sca;
  float4 sha = sca, shb = sca;
  if (MODE == 3) {
    sca = *(const float4*)(scale + f0);
    scb = *(const float4*)(scale + f0 + 4);
    sha = *(const float4*)(shift + f0);
    shb = *(const float4*)(shift + f0 + 4);
  }
  float4 s1a = make_float4(0.f, 0.f, 0.f, 0.f), s1b = s1a;
  float4 s2a = s1a, s2b = s1a;

  // ---- register prefetch buffers ----
  float4 pf[8];
  int pc = 0;
  const float4 zero4 = make_float4(0.f, 0.f, 0.f, 0.f);
  auto prefetch = [&](int tt) {
    const int pb = tt * PTILE;
#pragma unroll
    for (int i = 0; i < 8; ++i) {
      const int idx = tid + i * TPB;
      const int gp = pb + (idx >> 4);
      pf[i] = (gp < NPTS) ? *(const float4*)(x + (size_t)gp * DF + (idx & 15) * 4)
                          : zero4;
    }
    if (tid < PTILE) {
      const int gp = pb + tid;
      pc = (gp < NPTS) ? cluster[gp] : 0;
    }
  };

  int t = blockIdx.x;
  if (t < NTILES) prefetch(t);

  for (; t < NTILES; t += gridDim.x) {
    const int pbase = t * PTILE;
    __syncthreads();  // previous compute done reading xs
#pragma unroll
    for (int i = 0; i < 8; ++i) {
      const int idx = tid + i * TPB;
      *(float4*)(xs + (idx >> 4) * LSTR + (idx & 15) * 4) = pf[i];
    }
    if (tid < PTILE) cs[tid] = pc;
    __syncthreads();

    // issue next tile's global loads now; they complete during compute
    const int tn = t + gridDim.x;
    if (tn < NTILES) prefetch(tn);

    // ---- register-blocked GEMM ----
    float4 acca[4], accb[4];
#pragma unroll
    for (int pp = 0; pp < 4; ++pp) { acca[pp] = bva; accb[pp] = bvb; }
#pragma unroll 4
    for (int j4 = 0; j4 < 16; ++j4) {
      float4 wv[4][2];  // wv[e][h]: k = j4*4+e, features f0+4h..+3
#pragma unroll
      for (int e = 0; e < 4; ++e) {
        wv[e][0] = *(const float4*)(Wt + (j4 * 4 + e) * DF + f0);
        wv[e][1] = *(const float4*)(Wt + (j4 * 4 + e) * DF + f0 + 4);
      }
#pragma unroll
      for (int pp = 0; pp < 4; ++pp) {
        const float4 xv = *(const float4*)(xs + (pg * 4 + pp) * LSTR + j4 * 4);
        FMA_K(pp, xv.x, 0)
        FMA_K(pp, xv.y, 1)
        FMA_K(pp, xv.z, 2)
        FMA_K(pp, xv.w, 3)
      }
    }

    // ---- mode-specific epilogue ----
#pragma unroll
    for (int pp = 0; pp < 4; ++pp) {
      const int lp = pg * 4 + pp;
      const int p = pbase + lp;
      if (MODE == 0) {
        if (p < NPTS) {
          unsigned* dst = q_u + (size_t)cs[lp] * DF + f0;
          // q_u is monotone non-decreasing: stale read only under-reports,
          // so skipping when new <= cached is race-safe.
          const uint4 c0 = *(const uint4*)dst;
          const uint4 c1 = *(const uint4*)(dst + 4);
          unsigned e;
          e = f2o(acca[pp].x); if (e > c0.x) atomicMax(dst + 0, e);
          e = f2o(acca[pp].y); if (e > c0.y) atomicMax(dst + 1, e);
          e = f2o(acca[pp].z); if (e > c0.z) atomicMax(dst + 2, e);
          e = f2o(acca[pp].w); if (e > c0.w) atomicMax(dst + 3, e);
          e = f2o(accb[pp].x); if (e > c1.x) atomicMax(dst + 4, e);
          e = f2o(accb[pp].y); if (e > c1.y) atomicMax(dst + 5, e);
          e = f2o(accb[pp].z); if (e > c1.z) atomicMax(dst + 6, e);
          e = f2o(accb[pp].w); if (e > c1.w) atomicMax(dst + 7, e);
        }
      } else if (MODE == 1) {
        float partial = 0.f;
        if (p < NPTS) {
          const unsigned* qp = q_u + (size_t)cs[lp] * DF + f0;
          const uint4 q0 = *(const uint4*)qp;
          const uint4 q1 = *(const uint4*)(qp + 4);
          partial = o2f(q0.x) * acca[pp].x + o2f(q0.y) * acca[pp].y +
                    o2f(q0.z) * acca[pp].z + o2f(q0.w) * acca[pp].w +
                    o2f(q1.x) * accb[pp].x + o2f(q1.y) * accb[pp].y +
                    o2f(q1.z) * accb[pp].z + o2f(q1.w) * accb[pp].w;
        }
        // reduce across the 8 lanes (fg bits) sharing this point
        partial += __shfl_xor(partial, 1, 64);
        partial += __shfl_xor(partial, 2, 64);
        partial += __shfl_xor(partial, 4, 64);
        if (fg == 0 && p < NPTS) {
          Mv[p] = partial;
          const unsigned e = f2o(partial);
          unsigned* mm = mmax_u + cs[lp];
          if (e > *mm) atomicMax(mm, e);
        }
      } else {
        if (p < NPTS) {
          const int c = cs[lp];
          const float attn = __expf(Mv[p] - o2f(mmax_u[c])) / denom[c];
          float4 ha, hb;
          ha.x = attn * acca[pp].x; ha.y = attn * acca[pp].y;
          ha.z = attn * acca[pp].z; ha.w = attn * acca[pp].w;
          hb.x = attn * accb[pp].x; hb.y = attn * accb[pp].y;
          hb.z = attn * accb[pp].z; hb.w = attn * accb[pp].w;
          if (MODE == 2) {
            s1a.x += ha.x; s1a.y += ha.y; s1a.z += ha.z; s1a.w += ha.w;
            s1b.x += hb.x; s1b.y += hb.y; s1b.z += hb.z; s1b.w += hb.w;
            s2a.x += ha.x * ha.x; s2a.y += ha.y * ha.y;
            s2a.z += ha.z * ha.z; s2a.w += ha.w * ha.w;
            s2b.x += hb.x * hb.x; s2b.y += hb.y * hb.y;
            s2b.z += hb.z * hb.z; s2b.w += hb.w * hb.w;
          } else {
            float4 ra, rb;
            ra.x = fmaxf(fmaf(ha.x, sca.x, sha.x), 0.f);
            ra.y = fmaxf(fmaf(ha.y, sca.y, sha.y), 0.f);
            ra.z = fmaxf(fmaf(ha.z, sca.z, sha.z), 0.f);
            ra.w = fmaxf(fmaf(ha.w, sca.w, sha.w), 0.f);
            rb.x = fmaxf(fmaf(hb.x, scb.x, shb.x), 0.f);
            rb.y = fmaxf(fmaf(hb.y, scb.y, shb.y), 0.f);
            rb.z = fmaxf(fmaf(hb.z, scb.z, shb.z), 0.f);
            rb.w = fmaxf(fmaf(hb.w, scb.w, shb.w), 0.f);
            *(float4*)(out + (size_t)p * DF + f0) = ra;
            *(float4*)(out + (size_t)p * DF + f0 + 4) = rb;
          }
        }
      }
    }
  }

  if constexpr (MODE == 2) {
    // block-reduce BN partial sums; alias xs as scratch (done with tiles)
    __syncthreads();
    float* red = xs;  // [32 pg][64 f] for s1, +2048 for s2
    *(float4*)(red + pg * DF + f0) = s1a;
    *(float4*)(red + pg * DF + f0 + 4) = s1b;
    *(float4*)(red + 2048 + pg * DF + f0) = s2a;
    *(float4*)(red + 2048 + pg * DF + f0 + 4) = s2b;
    __syncthreads();
    if (tid < DF) {
      float a = 0.f, b = 0.f;
#pragma unroll
      for (int g = 0; g < 32; ++g) {
        a += red[g * DF + tid];
        b += red[2048 + g * DF + tid];
      }
      atomicAdd(sums + tid, a);
      atomicAdd(sums + DF + tid, b);
    }
  }
}

__global__ void denom_kernel(const float* __restrict__ Mv,
                             const int* __restrict__ cluster,
                             const unsigned* __restrict__ mmax_u,
                             float* __restrict__ denom) {
  int i = blockIdx.x * blockDim.x + threadIdx.x;
  if (i < NPTS) {
    int c = cluster[i];
    atomicAdd(denom + c, __expf(Mv[i] - o2f(mmax_u[c])));
  }
}

__global__ void finalize_kernel(const float* __restrict__ sums,
                                const float* __restrict__ gamma,
                                const float* __restrict__ beta,
                                float* __restrict__ scale,
                                float* __restrict__ shift) {
  int d = threadIdx.x;
  float mean = sums[d] * (1.0f / NPTS);
  float var = sums[DF + d] * (1.0f / NPTS) - mean * mean;
  float s = gamma[d] * rsqrtf(var + BN_EPS);
  scale[d] = s;
  shift[d] = fmaf(-mean, s, beta[d]);
}

extern "C" void kernel_launch(void* const* d_in, const int* in_sizes, int n_in,
                              void* d_out, int out_size, void* d_ws,
                              size_t ws_size, hipStream_t stream) {
  const float* x = (const float*)d_in[1];
  const int* cluster = (const int*)d_in[2];
  const float* Wv = (const float*)d_in[3];
  const float* bv = (const float*)d_in[4];
  const float* Wk = (const float*)d_in[5];
  const float* bk = (const float*)d_in[6];
  const float* Wq = (const float*)d_in[7];
  const float* bq = (const float*)d_in[8];
  const float* gamma = (const float*)d_in[9];
  const float* beta = (const float*)d_in[10];
  float* out = (float*)d_out;

  float* ws = (float*)d_ws;
  unsigned* q_u = (unsigned*)ws;
  unsigned* mmax_u = (unsigned*)(ws + 640000);
  float* denom = ws + 650000;
  float* sums = ws + 660000;
  float* scale = ws + 660128;
  float* shift = ws + 660192;
  float* Mv = ws + 660256;

  // zero q_u / mmax_u / denom / sums (0u == sortable "-inf" sentinel)
  hipMemsetAsync(d_ws, 0, 660256 * sizeof(float), stream);

  proj_kernel<0><<<NBLK, TPB, 0, stream>>>(x, cluster, Wq, bq, q_u, mmax_u,
                                           denom, Mv, sums, scale, shift, out);
  proj_kernel<1><<<NBLK, TPB, 0, stream>>>(x, cluster, Wk, bk, q_u, mmax_u,
                                           denom, Mv, sums, scale, shift, out);
  denom_kernel<<<(NPTS + 255) / 256, 256, 0, stream>>>(Mv, cluster, mmax_u,
                                                       denom);
  proj_kernel<2><<<NBLK, TPB, 0, stream>>>(x, cluster, Wv, bv, q_u, mmax_u,
                                           denom, Mv, sums, scale, shift, out);
  finalize_kernel<<<1, 64, 0, stream>>>(sums, gamma, beta, scale, shift);
  proj_kernel<3><<<NBLK, TPB, 0, stream>>>(x, cluster, Wv, bv, q_u, mmax_u,
                                           denom, Mv, sums, scale, shift, out);
}